// Round 5
// baseline (243.958 us; speedup 1.0000x reference)
//
#include <hip/hip_runtime.h>

// ---------------- types / helpers ----------------
typedef __bf16 bf16;
typedef __attribute__((ext_vector_type(8)))  bf16     bf16x8;
typedef __attribute__((ext_vector_type(4)))  bf16     bf16x4;
typedef __attribute__((ext_vector_type(16))) float    f32x16;
typedef __attribute__((ext_vector_type(4)))  float    f32x4;
typedef __attribute__((ext_vector_type(4)))  unsigned uint4v;
typedef __attribute__((ext_vector_type(2)))  unsigned uint2v;

#define SLEN 4096
#define HDIM 64
#define EMB 512
#define SCALE_LOG2E 0.1803336100254854f  /* 0.125 * log2(e), folded into Q at projection */

__device__ __forceinline__ f32x16 mfma32(bf16x8 a, bf16x8 b, f32x16 c) {
  return __builtin_amdgcn_mfma_f32_32x32x16_bf16(a, b, c, 0, 0, 0);
}
__device__ __forceinline__ f32x4 mfma16(bf16x8 a, bf16x8 b, f32x4 c) {
  return __builtin_amdgcn_mfma_f32_16x16x32_bf16(a, b, c, 0, 0, 0);
}

// async global->LDS, 16B per lane; LDS dest is wave-uniform base + lane*16
__device__ __forceinline__ void cp16(const void* g, const void* l) {
  __builtin_amdgcn_global_load_lds(
      (__attribute__((address_space(1))) unsigned int*)(unsigned long long)g,
      (__attribute__((address_space(3))) unsigned int*)(unsigned int)(unsigned long long)l,
      16, 0, 0);
}

__device__ __forceinline__ unsigned pk2(float a, float b) {
  unsigned short ua = __builtin_bit_cast(unsigned short, (bf16)a);
  unsigned short ub = __builtin_bit_cast(unsigned short, (bf16)b);
  return (unsigned)ua | ((unsigned)ub << 16);
}

// ---------------- kernel 1: QKV projections (MFMA), Q pre-scaled ----------------
__global__ __launch_bounds__(256, 2) void proj_qkv(
    const float* __restrict__ key, const float* __restrict__ query, const float* __restrict__ value,
    const float* __restrict__ Wq, const float* __restrict__ Wk, const float* __restrict__ Wv,
    bf16* __restrict__ Qb, bf16* __restrict__ Kb, bf16* __restrict__ VT)
{
  __shared__ __align__(16) bf16 tile[128][64];
  const int tid = threadIdx.x, w = tid >> 6, lane = tid & 63, l31 = lane & 31, lh = lane >> 5;
  const int r0 = blockIdx.x * 128;
  const int m0 = r0 + w * 32;

  #pragma unroll
  for (int p = 0; p < 3; ++p) {
    const float* X = (p == 0) ? query : (p == 1) ? key : value;
    const float* W = (p == 0) ? Wq    : (p == 1) ? Wk  : Wv;

    bf16x8 af[4];
    {
      const float* xr = X + (size_t)(m0 + l31) * 64 + 8 * lh;
      #pragma unroll
      for (int c = 0; c < 4; ++c) {
        f32x4 lo = *(const f32x4*)(xr + c * 16);
        f32x4 hi = *(const f32x4*)(xr + c * 16 + 4);
        bf16x8 v;
        #pragma unroll
        for (int j = 0; j < 4; ++j) { v[j] = (bf16)lo[j]; v[4 + j] = (bf16)hi[j]; }
        af[c] = v;
      }
    }
    bf16x8 bfr[2][4];
    #pragma unroll
    for (int nb = 0; nb < 2; ++nb) {
      const float* wr = W + (size_t)(l31 + 32 * nb) * 64 + 8 * lh;
      #pragma unroll
      for (int c = 0; c < 4; ++c) {
        f32x4 lo = *(const f32x4*)(wr + c * 16);
        f32x4 hi = *(const f32x4*)(wr + c * 16 + 4);
        bf16x8 v;
        #pragma unroll
        for (int j = 0; j < 4; ++j) { v[j] = (bf16)lo[j]; v[4 + j] = (bf16)hi[j]; }
        bfr[nb][c] = v;
      }
    }
    f32x16 a0, a1;
    #pragma unroll
    for (int r = 0; r < 16; ++r) { a0[r] = 0.f; a1[r] = 0.f; }
    #pragma unroll
    for (int c = 0; c < 4; ++c) {
      a0 = mfma32(af[c], bfr[0][c], a0);
      a1 = mfma32(af[c], bfr[1][c], a1);
    }

    const float qs = (p == 0) ? SCALE_LOG2E : 1.0f;
    __syncthreads();
    #pragma unroll
    for (int r = 0; r < 16; ++r) {
      const int row = w * 32 + (r & 3) + 8 * (r >> 2) + 4 * lh;
      tile[row][l31]      = (bf16)(a0[r] * qs);
      tile[row][l31 + 32] = (bf16)(a1[r] * qs);
    }
    __syncthreads();

    if (p < 2) {
      bf16* OUT = p ? Kb : Qb;
      const int rloc = tid >> 1, half = tid & 1;
      const int rg = r0 + rloc, bs = rg >> 3, h = rg & 7, b = bs >> 12, sidx = bs & 4095;
      bf16* dst = OUT + (((size_t)(b * 8 + h) * SLEN + sidx) * 64 + half * 32);
      const bf16* srcp = &tile[rloc][half * 32];
      #pragma unroll
      for (int u = 0; u < 4; ++u) *(uint4v*)(dst + u * 8) = *(const uint4v*)(srcp + u * 8);
    } else {
      const int h = tid >> 5, d0 = tid & 31;
      const int b = blockIdx.x >> 8, s0 = (blockIdx.x * 16) & 4095;
      #pragma unroll
      for (int dh = 0; dh < 2; ++dh) {
        const int dd = d0 + 32 * dh;
        unsigned pk4[8];
        #pragma unroll
        for (int t2 = 0; t2 < 8; ++t2) {
          unsigned short ua = __builtin_bit_cast(unsigned short, tile[(2 * t2) * 8 + h][dd]);
          unsigned short ub = __builtin_bit_cast(unsigned short, tile[(2 * t2 + 1) * 8 + h][dd]);
          pk4[t2] = (unsigned)ua | ((unsigned)ub << 16);
        }
        bf16* dst = VT + ((size_t)(b * 8 + h) * 64 + dd) * SLEN + s0;
        uint4v A; A[0] = pk4[0]; A[1] = pk4[1]; A[2] = pk4[2]; A[3] = pk4[3];
        uint4v Bv; Bv[0] = pk4[4]; Bv[1] = pk4[5]; Bv[2] = pk4[6]; Bv[3] = pk4[7];
        *(uint4v*)(dst) = A;
        *(uint4v*)(dst + 8) = Bv;
      }
    }
  }
}

// ---------------- kernel 2: mask -> per-(g,q) step bytes ----------------
// MW4[g][q][s] : bit (4b + r) = mask[q][32s + 16b + 4g + r]
// (g = lane>>4 in attn; b = 16-kv block; r = C/D reg index)
__global__ void pack_mask(const int* __restrict__ mask, unsigned char* __restrict__ MW4)
{
  const int w = threadIdx.x >> 6, lane = threadIdx.x & 63;
  const int q = blockIdx.x * 4 + w;
  const int* row = mask + (size_t)q * SLEN;
  unsigned long long mine = 0ull;
  #pragma unroll 4
  for (int i = 0; i < 64; ++i) {
    unsigned long long b = __ballot(row[i * 64 + lane] != 0);
    if (i == lane) mine = b;
  }
  const unsigned lo = (unsigned)mine, hi = (unsigned)(mine >> 32);
  #pragma unroll
  for (int gg = 0; gg < 4; ++gg) {
    unsigned b0 = ((lo >> (4 * gg)) & 0xFu) | (((lo >> (16 + 4 * gg)) & 0xFu) << 4);
    unsigned b1 = ((hi >> (4 * gg)) & 0xFu) | (((hi >> (16 + 4 * gg)) & 0xFu) << 4);
    *(unsigned short*)(MW4 + ((size_t)gg * 4096 + q) * 128 + 2 * lane) =
        (unsigned short)(b0 | (b1 << 8));
  }
}

// ---------------- kernel 3: Wo -> hi/lo bf16 planes ----------------
__global__ void wo_split(const float* __restrict__ Wo, bf16* __restrict__ WH, bf16* __restrict__ WL)
{
  const int i = (blockIdx.x * 256 + threadIdx.x) * 4;
  f32x4 v = *(const f32x4*)(Wo + i);
  bf16x4 h, l;
  #pragma unroll
  for (int j = 0; j < 4; ++j) { h[j] = (bf16)v[j]; l[j] = (bf16)(v[j] - (float)h[j]); }
  *(bf16x4*)(WH + i) = h;
  *(bf16x4*)(WL + i) = l;
}

// ---------------- kernel 4: flash attention, 16x16 MFMA, q=16/wave ----------------
// Block: 4 waves x 16 q-rows (64 q). KV tiles of 64, double-buffered LDS, frag-linear.
// Swapped QK^T (A=K, B=Q): C/D row = kv = 4*(lane>>4)+reg, col = q = lane&15.
// P redistributed to PV B-operand via 8x ds_bpermute + cndmask (no LDS storage).
// LDS: K buf0 [0,8K) buf1 [8K,16K); V buf0 [16K,24K) buf1 [24K,32K); frag f at f*1024.
__global__ __launch_bounds__(256, 4) void attn_kernel(
    const bf16* __restrict__ Qb, const bf16* __restrict__ Kb, const bf16* __restrict__ VT,
    const unsigned char* __restrict__ MW4,
    bf16* __restrict__ ctxh, bf16* __restrict__ ctxl)
{
  __shared__ __align__(16) unsigned char smem[32768];
  unsigned char* const Ksm = smem;
  unsigned char* const Vsm = smem + 16384;

  const int tid = threadIdx.x, w = tid >> 6, lane = tid & 63;
  const int g = lane >> 4, q15 = lane & 15;
  const int bh = blockIdx.x >> 6;
  const int q0w = (blockIdx.x & 63) * 64 + w * 16;

  // Q fragments (B operand): qf[c] elem j = Q[q0w+q15][c*32 + 8g + j]  (pre-scaled)
  const bf16* qp = Qb + ((size_t)bh * SLEN + q0w + q15) * HDIM + 8 * g;
  const bf16x8 qf0 = *(const bf16x8*)(qp);
  const bf16x8 qf1 = *(const bf16x8*)(qp + 32);

  // staging: wave w owns K frags {2w,2w+1} (f = sub*4+blk*2+c) and V frags {2w,2w+1} (f = sub*4+db)
  const int fk0 = 2 * w, fk1 = 2 * w + 1;
  const bf16* kp0 = Kb + ((size_t)bh * SLEN + (fk0 >> 2) * 32 + ((fk0 >> 1) & 1) * 16 + q15) * HDIM
                       + (fk0 & 1) * 32 + 8 * g;
  const bf16* kp1 = Kb + ((size_t)bh * SLEN + (fk1 >> 2) * 32 + ((fk1 >> 1) & 1) * 16 + q15) * HDIM
                       + (fk1 & 1) * 32 + 8 * g;
  const bf16* vp0 = VT + ((size_t)(bh * 64 + (fk0 & 3) * 16 + q15)) * SLEN + (fk0 >> 2) * 32 + 8 * g;
  const bf16* vp1 = VT + ((size_t)(bh * 64 + (fk1 & 3) * 16 + q15)) * SLEN + (fk1 >> 2) * 32 + 8 * g;

  unsigned char* const dK0a = Ksm + fk0 * 1024;          // buf0
  unsigned char* const dK1a = Ksm + fk1 * 1024;
  unsigned char* const dK0b = Ksm + 8192 + fk0 * 1024;   // buf1
  unsigned char* const dK1b = Ksm + 8192 + fk1 * 1024;
  unsigned char* const dV0a = Vsm + fk0 * 1024;
  unsigned char* const dV1a = Vsm + fk1 * 1024;
  unsigned char* const dV0b = Vsm + 8192 + fk0 * 1024;
  unsigned char* const dV1b = Vsm + 8192 + fk1 * 1024;

  f32x4 o0 = {0.f, 0.f, 0.f, 0.f}, o1 = o0, o2 = o0, o3 = o0;
  const f32x4 Z4 = {0.f, 0.f, 0.f, 0.f};
  float la0 = 0.f, la1 = 0.f, la2 = 0.f, la3 = 0.f;

  // bpermute lane indices (byte addr = src lane * 4); consumer g' pulls from g = 2(g'&1)[+1]
  const int idx0 = (32 * (g & 1) + q15) * 4;
  const int idx1 = idx0 + 64;
  const bool bhi = (g >= 2);

  const unsigned char* mp = MW4 + ((size_t)g * 4096 + q0w + q15) * 128;
  unsigned mw = *(const unsigned*)(mp);

  // prologue: stage tile 0 -> buf0
  cp16(kp0, dK0a); cp16(kp1, dK1a); cp16(vp0, dV0a); cp16(vp1, dV1a);
  kp0 += 4096; kp1 += 4096; vp0 += 64; vp1 += 64;
  __syncthreads();

  const int lb = lane * 16;

#define LDK(BUF, U, BLK, C) \
  (*(const bf16x8*)(Ksm + (BUF) * 8192 + (((U) * 4 + (BLK) * 2 + (C)) * 1024) + lb))
#define LDV(BUF, U, DB) \
  (*(const bf16x8*)(Vsm + (BUF) * 8192 + (((U) * 4 + (DB)) * 1024) + lb))

#define MEXP(dst, sv, POS) { \
  float e_ = __builtin_amdgcn_exp2f(sv); \
  unsigned k_ = (unsigned)(((int)(mw << (31 - (POS)))) >> 31); \
  dst = __builtin_bit_cast(float, __builtin_bit_cast(unsigned, e_) & k_); }

#define SUBSTEP(BUF, U, BYTE) { \
  f32x4 sb0 = mfma16(LDK(BUF, U, 0, 0), qf0, Z4); \
  sb0 = mfma16(LDK(BUF, U, 0, 1), qf1, sb0); \
  f32x4 sb1 = mfma16(LDK(BUF, U, 1, 0), qf0, Z4); \
  sb1 = mfma16(LDK(BUF, U, 1, 1), qf1, sb1); \
  float p00, p01, p02, p03, p10, p11, p12, p13; \
  MEXP(p00, sb0[0], 8 * (BYTE) + 0) MEXP(p01, sb0[1], 8 * (BYTE) + 1) \
  MEXP(p02, sb0[2], 8 * (BYTE) + 2) MEXP(p03, sb0[3], 8 * (BYTE) + 3) \
  MEXP(p10, sb1[0], 8 * (BYTE) + 4) MEXP(p11, sb1[1], 8 * (BYTE) + 5) \
  MEXP(p12, sb1[2], 8 * (BYTE) + 6) MEXP(p13, sb1[3], 8 * (BYTE) + 7) \
  la0 += p00 + p10; la1 += p01 + p11; la2 += p02 + p12; la3 += p03 + p13; \
  const unsigned W00 = pk2(p00, p01), W01 = pk2(p02, p03); \
  const unsigned W10 = pk2(p10, p11), W11 = pk2(p12, p13); \
  const unsigned a00 = (unsigned)__builtin_amdgcn_ds_bpermute(idx0, (int)W00); \
  const unsigned a10 = (unsigned)__builtin_amdgcn_ds_bpermute(idx0, (int)W10); \
  const unsigned a01 = (unsigned)__builtin_amdgcn_ds_bpermute(idx0, (int)W01); \
  const unsigned a11 = (unsigned)__builtin_amdgcn_ds_bpermute(idx0, (int)W11); \
  const unsigned b00 = (unsigned)__builtin_amdgcn_ds_bpermute(idx1, (int)W00); \
  const unsigned b10 = (unsigned)__builtin_amdgcn_ds_bpermute(idx1, (int)W10); \
  const unsigned b01 = (unsigned)__builtin_amdgcn_ds_bpermute(idx1, (int)W01); \
  const unsigned b11 = (unsigned)__builtin_amdgcn_ds_bpermute(idx1, (int)W11); \
  uint4v fw; \
  fw[0] = bhi ? a10 : a00;  fw[1] = bhi ? a11 : a01; \
  fw[2] = bhi ? b10 : b00;  fw[3] = bhi ? b11 : b01; \
  const bf16x8 bp = __builtin_bit_cast(bf16x8, fw); \
  o0 = mfma16(LDV(BUF, U, 0), bp, o0); o1 = mfma16(LDV(BUF, U, 1), bp, o1); \
  o2 = mfma16(LDV(BUF, U, 2), bp, o2); o3 = mfma16(LDV(BUF, U, 3), bp, o3); \
}

#define TILE(BUF, BYTE, DK0, DK1, DV0, DV1) { \
  cp16(kp0, DK0); cp16(kp1, DK1); cp16(vp0, DV0); cp16(vp1, DV1); \
  kp0 += 4096; kp1 += 4096; vp0 += 64; vp1 += 64; \
  SUBSTEP(BUF, 0, (BYTE)) \
  SUBSTEP(BUF, 1, (BYTE) + 1) \
  __syncthreads(); \
}

  for (int tp = 0; tp < 32; ++tp) {
    const unsigned mwn = *(const unsigned*)(mp + 4);
    TILE(0, 0, dK0b, dK1b, dV0b, dV1b)   // compute tile 2tp (buf0); stage 2tp+1 -> buf1
    TILE(1, 2, dK0a, dK1a, dV0a, dV1a)   // compute tile 2tp+1 (buf1); stage 2tp+2 -> buf0
    mw = mwn; mp += 4;
  }

  // ---- epilogue (per-wave, no cross-wave combine) ----
  float lsum = (la0 + la1) + (la2 + la3);
  lsum += __shfl_xor(lsum, 16);
  lsum += __shfl_xor(lsum, 32);
  const float inv = 1.f / lsum;
  #pragma unroll
  for (int r = 0; r < 4; ++r) { o0[r] *= inv; o1[r] *= inv; o2[r] *= inv; o3[r] *= inv; }

  __syncthreads();  // all waves done reading K/V buffers before smem reuse
  unsigned char* const Tr = smem + w * 4096;       // per-wave [16 q][stride 136B] bf16
  const int trw = q15 * 136 + 8 * g;               // (q, d = 16db+4g) -> + 32*db
  const int qq = lane >> 2, part = lane & 3;
  const int rb = qq * 136 + part * 32;
  bf16* dsth = ctxh + ((size_t)bh * SLEN + q0w + qq) * HDIM + part * 16;
  bf16* dstl = ctxl + ((size_t)bh * SLEN + q0w + qq) * HDIM + part * 16;

  // hi plane
  { uint2v t; t[0] = pk2(o0[0], o0[1]); t[1] = pk2(o0[2], o0[3]); *(uint2v*)(Tr + trw)      = t; }
  { uint2v t; t[0] = pk2(o1[0], o1[1]); t[1] = pk2(o1[2], o1[3]); *(uint2v*)(Tr + trw + 32) = t; }
  { uint2v t; t[0] = pk2(o2[0], o2[1]); t[1] = pk2(o2[2], o2[3]); *(uint2v*)(Tr + trw + 64) = t; }
  { uint2v t; t[0] = pk2(o3[0], o3[1]); t[1] = pk2(o3[2], o3[3]); *(uint2v*)(Tr + trw + 96) = t; }
  {
    uint2v r0 = *(const uint2v*)(Tr + rb);
    uint2v r1 = *(const uint2v*)(Tr + rb + 8);
    uint2v r2 = *(const uint2v*)(Tr + rb + 16);
    uint2v r3 = *(const uint2v*)(Tr + rb + 24);
    uint4v s0; s0[0] = r0[0]; s0[1] = r0[1]; s0[2] = r1[0]; s0[3] = r1[1];
    uint4v s1; s1[0] = r2[0]; s1[1] = r2[1]; s1[2] = r3[0]; s1[3] = r3[1];
    *(uint4v*)(dsth) = s0;
    *(uint4v*)(dsth + 8) = s1;
  }
  // lo plane
  f32x4 l0, l1, l2, l3;
  #pragma unroll
  for (int r = 0; r < 4; ++r) {
    l0[r] = o0[r] - (float)(bf16)o0[r];
    l1[r] = o1[r] - (float)(bf16)o1[r];
    l2[r] = o2[r] - (float)(bf16)o2[r];
    l3[r] = o3[r] - (float)(bf16)o3[r];
  }
  { uint2v t; t[0] = pk2(l0[0], l0[1]); t[1] = pk2(l0[2], l0[3]); *(uint2v*)(Tr + trw)      = t; }
  { uint2v t; t[0] = pk2(l1[0], l1[1]); t[1] = pk2(l1[2], l1[3]); *(uint2v*)(Tr + trw + 32) = t; }
  { uint2v t; t[0] = pk2(l2[0], l2[1]); t[1] = pk2(l2[2], l2[3]); *(uint2v*)(Tr + trw + 64) = t; }
  { uint2v t; t[0] = pk2(l3[0], l3[1]); t[1] = pk2(l3[2], l3[3]); *(uint2v*)(Tr + trw + 96) = t; }
  {
    uint2v r0 = *(const uint2v*)(Tr + rb);
    uint2v r1 = *(const uint2v*)(Tr + rb + 8);
    uint2v r2 = *(const uint2v*)(Tr + rb + 16);
    uint2v r3 = *(const uint2v*)(Tr + rb + 24);
    uint4v s0; s0[0] = r0[0]; s0[1] = r0[1]; s0[2] = r1[0]; s0[3] = r1[1];
    uint4v s1; s1[0] = r2[0]; s1[1] = r2[1]; s1[2] = r3[0]; s1[3] = r3[1];
    *(uint4v*)(dstl) = s0;
    *(uint4v*)(dstl + 8) = s1;
  }
#undef LDK
#undef LDV
#undef MEXP
#undef SUBSTEP
#undef TILE
}

// ---------------- kernel 5: output projection (hi/lo split GEMM) ----------------
__global__ __launch_bounds__(256, 2) void out_proj(
    const bf16* __restrict__ CH, const bf16* __restrict__ CL,
    const bf16* __restrict__ WH, const bf16* __restrict__ WL,
    const float* __restrict__ bo, float* __restrict__ out)
{
  __shared__ __align__(16) bf16 Af[2][4][4][64][8];  // 32KB
  const int tid = threadIdx.x, w = tid >> 6, lane = tid & 63, l31 = lane & 31, lh = lane >> 5;
  const int mt = blockIdx.x >> 3, nt = blockIdx.x & 7;
  const int bs0 = mt * 128, n0 = nt * 64;
  const int b = bs0 >> 12, sbase = bs0 & 4095;

  f32x16 a0, a1;
  #pragma unroll
  for (int r = 0; r < 16; ++r) { a0[r] = 0.f; a1[r] = 0.f; }

  for (int kk = 0; kk < 8; ++kk) {
    __syncthreads();
    #pragma unroll
    for (int qq = 0; qq < 8; ++qq) {
      const int fid = w * 8 + qq, pl = fid >> 4, mb = (fid >> 2) & 3, c = fid & 3;
      const bf16* src = (pl ? CL : CH) +
          ((size_t)(b * 8 + kk) * SLEN + sbase + 32 * mb + l31) * 64 + 16 * c + 8 * lh;
      cp16(src, &Af[pl][mb][c][0][0]);
    }
    __syncthreads();

    bf16x8 bh0[4], bl0[4], bh1[4], bl1[4], ah[4], al[4];
    #pragma unroll
    for (int c = 0; c < 4; ++c) {
      const size_t o0off = (size_t)(n0 + l31) * EMB + kk * 64 + 16 * c + 8 * lh;
      const size_t o1off = (size_t)(n0 + l31 + 32) * EMB + kk * 64 + 16 * c + 8 * lh;
      bh0[c] = *(const bf16x8*)(WH + o0off);
      bl0[c] = *(const bf16x8*)(WL + o0off);
      bh1[c] = *(const bf16x8*)(WH + o1off);
      bl1[c] = *(const bf16x8*)(WL + o1off);
      ah[c] = *(const bf16x8*)(&Af[0][w][c][lane][0]);
      al[c] = *(const bf16x8*)(&Af[1][w][c][lane][0]);
    }
    #pragma unroll
    for (int c = 0; c < 4; ++c) {
      a0 = mfma32(ah[c], bh0[c], a0);
      a0 = mfma32(ah[c], bl0[c], a0);
      a0 = mfma32(al[c], bh0[c], a0);
      a1 = mfma32(ah[c], bh1[c], a1);
      a1 = mfma32(ah[c], bl1[c], a1);
      a1 = mfma32(al[c], bh1[c], a1);
    }
  }

  const float bv0 = bo[n0 + l31], bv1 = bo[n0 + l31 + 32];
  #pragma unroll
  for (int r = 0; r < 16; ++r) {
    const int row = bs0 + w * 32 + (r & 3) + 8 * (r >> 2) + 4 * lh;
    out[(size_t)row * EMB + n0 + l31]      = a0[r] + bv0;
    out[(size_t)row * EMB + n0 + l31 + 32] = a1[r] + bv1;
  }
}

// ---------------- launch ----------------
extern "C" void kernel_launch(void* const* d_in, const int* in_sizes, int n_in,
                              void* d_out, int out_size, void* d_ws, size_t ws_size,
                              hipStream_t stream)
{
  (void)in_sizes; (void)n_in; (void)out_size; (void)ws_size;
  const float* key   = (const float*)d_in[0];
  const float* query = (const float*)d_in[1];
  const float* value = (const float*)d_in[2];
  const int*   mask  = (const int*)d_in[3];
  const float* Wq    = (const float*)d_in[4];
  const float* Wk    = (const float*)d_in[5];
  const float* Wv    = (const float*)d_in[6];
  const float* Wo    = (const float*)d_in[7];
  const float* bo    = (const float*)d_in[8];
  float* out = (float*)d_out;

  char* ws = (char*)d_ws;                       // ~43.5 MB used
  bf16* Qb = (bf16*)(ws);                       // 8 MB  [BH][S][64] (pre-scaled)
  bf16* Kb = (bf16*)(ws + (8ull  << 20));       // 8 MB  [BH][S][64]
  bf16* VT = (bf16*)(ws + (16ull << 20));       // 8 MB  [BH][64][S]
  unsigned char* MW4 = (unsigned char*)(ws + (24ull << 20));  // 2 MB [g][q][128 step bytes]
  bf16* CH = (bf16*)(ws + (26ull << 20));       // 8 MB  ctx hi
  bf16* CL = (bf16*)(ws + (34ull << 20));       // 8 MB  ctx lo
  bf16* WH = (bf16*)(ws + (42ull << 20));       // 512 KB
  bf16* WL = (bf16*)(ws + (42ull << 20) + (512ull << 10));

  proj_qkv<<<512, 256, 0, stream>>>(key, query, value, Wq, Wk, Wv, Qb, Kb, VT);
  pack_mask<<<1024, 256, 0, stream>>>(mask, MW4);
  wo_split<<<256, 256, 0, stream>>>(Wo, WH, WL);
  attn_kernel<<<1024, 256, 0, stream>>>(Qb, Kb, VT, MW4, CH, CL);
  out_proj<<<512, 256, 0, stream>>>(CH, CL, WH, WL, bo, out);
}